// Round 1
// baseline (15101.254 us; speedup 1.0000x reference)
//
#include <hip/hip_runtime.h>
#include <hip/hip_bf16.h>
#include <math.h>

// ---------------- problem constants ----------------
#define B_    4
#define S_    1024
#define D_    2048
#define HQ_   16
#define HKV_  8
#define HD_   128
#define GRP_  (HQ_ / HKV_)   // 2
#define E_    8
#define KTOP_ 2
#define FE_   1024
#define FS_   8192
#define NT_   (B_ * S_)      // 4096 tokens
#define EPS_  1e-6f

// jax.nn.gelu default is approximate=True (tanh form)
__device__ __forceinline__ float gelu_tanh(float x) {
    float x3 = x * x * x;
    float t  = tanhf(0.79788456080286535588f * (x + 0.044715f * x3));
    return 0.5f * x * (1.0f + t);
}

// ---------------- RMSNorm over D=2048 rows ----------------
// out = rms(in)*scale (+ addend). Caches row values in regs so in==out is safe.
__global__ __launch_bounds__(256) void rms_kernel(
    const float* in, const float* scale, const float* addend, float* out)
{
    const int row = blockIdx.x;
    const int tid = threadIdx.x;
    const float* rp = in + (size_t)row * D_;
    float vals[8];
    float ss = 0.f;
#pragma unroll
    for (int i = 0; i < 8; ++i) {
        int d = tid + i * 256;
        float v = rp[d];
        vals[i] = v;
        ss += v * v;
    }
    __shared__ float red[256];
    red[tid] = ss;
    __syncthreads();
    for (int s = 128; s > 0; s >>= 1) {
        if (tid < s) red[tid] += red[tid + s];
        __syncthreads();
    }
    float rn = 1.0f / sqrtf(red[0] / (float)D_ + EPS_);
    float* op = out + (size_t)row * D_;
    const float* ap = addend ? addend + (size_t)row * D_ : nullptr;
#pragma unroll
    for (int i = 0; i < 8; ++i) {
        int d = tid + i * 256;
        float v = vals[i] * rn * scale[d];
        if (ap) v += ap[d];
        op[d] = v;
    }
}

// ---------------- per-head RMS (+ optional RoPE), HD=128 ----------------
// qk layout: [token, head, HD] flattened; one block (128 thr) per (token,head)
__global__ __launch_bounds__(128) void headnorm_rope_kernel(
    float* qk, const float* nscale, const int* positions, int nheads, int do_rope)
{
    const int r = blockIdx.x;            // token*nheads + head
    const int token = r / nheads;
    const int d = threadIdx.x;
    float* p = qk + (size_t)r * HD_;
    float v = p[d];
    __shared__ float red[128];
    red[d] = v * v;
    __syncthreads();
    for (int s = 64; s > 0; s >>= 1) {
        if (d < s) red[d] += red[d + s];
        __syncthreads();
    }
    float rn = 1.0f / sqrtf(red[0] / (float)HD_ + EPS_);
    float nv = v * rn * nscale[d];
    if (!do_rope) { p[d] = nv; return; }
    __shared__ float buf[128];
    buf[d] = nv;
    __syncthreads();
    int pos = positions[token];
    int j = d & 63;
    // inv = 10000^(-j/64), mirrors reference in f32
    float inv = powf(10000.0f, -(float)j / 64.0f);
    float ang = (float)pos * inv;
    float sn, cs;
    sincosf(ang, &sn, &cs);
    float x1 = buf[j], x2 = buf[j + 64];
    float o = (d < 64) ? (x1 * cs - x2 * sn) : (x2 * cs + x1 * sn);
    p[d] = o;
}

// ---------------- tiled SGEMM, f32 ----------------
// C[M,N] = A[M,K] @ B[K,N]   (all row-major, M%64==N%64==K%16==0)
// EPI 0: plain store
// EPI 1: dual-B: C = gelu(A@B0) * (A@B1)
// EPI 2: C (+)= rowscale[m*rs_stride] * (A@B0)   (accflag selects accumulate)
#define BM 64
#define BN 64
#define BK 16
template <int EPI>
__global__ __launch_bounds__(256) void sgemm_kernel(
    const float* __restrict__ A, const float* __restrict__ B0,
    const float* __restrict__ B1, float* __restrict__ C,
    int M, int N, int Kd,
    const float* __restrict__ rowscale, int rs_stride, int accflag)
{
    __shared__ float As[BK][BM + 4];
    __shared__ float Bs0[BK][BN + 4];
    __shared__ float Bs1[(EPI == 1) ? BK : 1][BN + 4];

    const int tid = threadIdx.x;
    const int bm = blockIdx.y * BM;
    const int bn = blockIdx.x * BN;
    const int tx = tid & 15;       // n dir
    const int ty = tid >> 4;       // m dir

    float acc0[4][4] = {};
    float acc1[4][4] = {};

    const int arow = tid >> 2;          // 0..63
    const int acol = (tid & 3) * 4;     // k offset 0/4/8/12
    const int brow = tid >> 4;          // 0..15 (k)
    const int bcol = (tid & 15) * 4;    // n offset

    const float* Aptr = A + (size_t)(bm + arow) * Kd + acol;
    const float* B0p  = B0 + (size_t)brow * N + bn + bcol;
    const float* B1p  = (EPI == 1) ? (B1 + (size_t)brow * N + bn + bcol) : nullptr;

    for (int k0 = 0; k0 < Kd; k0 += BK) {
        float4 av = *(const float4*)Aptr;
        Aptr += BK;
        As[acol + 0][arow] = av.x;
        As[acol + 1][arow] = av.y;
        As[acol + 2][arow] = av.z;
        As[acol + 3][arow] = av.w;
        *(float4*)&Bs0[brow][bcol] = *(const float4*)B0p;
        B0p += (size_t)BK * N;
        if (EPI == 1) {
            *(float4*)&Bs1[brow][bcol] = *(const float4*)B1p;
            B1p += (size_t)BK * N;
        }
        __syncthreads();
#pragma unroll
        for (int kk = 0; kk < BK; ++kk) {
            float4 a4 = *(const float4*)&As[kk][ty * 4];
            float4 b4 = *(const float4*)&Bs0[kk][tx * 4];
            float a[4] = {a4.x, a4.y, a4.z, a4.w};
            float b[4] = {b4.x, b4.y, b4.z, b4.w};
#pragma unroll
            for (int i = 0; i < 4; ++i)
#pragma unroll
                for (int j = 0; j < 4; ++j) acc0[i][j] += a[i] * b[j];
            if (EPI == 1) {
                float4 c4 = *(const float4*)&Bs1[kk][tx * 4];
                float b1v[4] = {c4.x, c4.y, c4.z, c4.w};
#pragma unroll
                for (int i = 0; i < 4; ++i)
#pragma unroll
                    for (int j = 0; j < 4; ++j) acc1[i][j] += a[i] * b1v[j];
            }
        }
        __syncthreads();
    }

    if (EPI == 0) {
#pragma unroll
        for (int i = 0; i < 4; ++i) {
            size_t ci = (size_t)(bm + ty * 4 + i) * N + bn + tx * 4;
            float4 v = {acc0[i][0], acc0[i][1], acc0[i][2], acc0[i][3]};
            *(float4*)&C[ci] = v;
        }
    } else if (EPI == 1) {
#pragma unroll
        for (int i = 0; i < 4; ++i) {
            size_t ci = (size_t)(bm + ty * 4 + i) * N + bn + tx * 4;
            float4 v;
            v.x = gelu_tanh(acc0[i][0]) * acc1[i][0];
            v.y = gelu_tanh(acc0[i][1]) * acc1[i][1];
            v.z = gelu_tanh(acc0[i][2]) * acc1[i][2];
            v.w = gelu_tanh(acc0[i][3]) * acc1[i][3];
            *(float4*)&C[ci] = v;
        }
    } else {
#pragma unroll
        for (int i = 0; i < 4; ++i) {
            int m = bm + ty * 4 + i;
            float rs = rowscale[(size_t)m * rs_stride];
            size_t ci = (size_t)m * N + bn + tx * 4;
#pragma unroll
            for (int j = 0; j < 4; ++j) {
                float v = rs * acc0[i][j];
                if (accflag) v += C[ci + j];
                C[ci + j] = v;
            }
        }
    }
}

// ---------------- causal attention, one block per (b,h,q) ----------------
// No softmax scale (reference has none). Q:[token,HQ,HD] K/V:[token,HKV,HD]
__global__ __launch_bounds__(256) void attn_kernel(
    const float* __restrict__ Q, const float* __restrict__ Kb,
    const float* __restrict__ Vb, float* __restrict__ O)
{
    const int idx = blockIdx.x;
    const int q = idx % S_;
    const int h = (idx / S_) % HQ_;
    const int b = idx / (S_ * HQ_);
    const int kv = h / GRP_;
    const int tid = threadIdx.x;

    __shared__ float qv[HD_];
    __shared__ float sc[S_];
    __shared__ float red[256];

    const float* qp = Q + ((size_t)(b * S_ + q) * HQ_ + h) * HD_;
    if (tid < HD_) qv[tid] = qp[tid];
    __syncthreads();

    const int kn = q + 1;
    float lmax = -3.4e38f;
    for (int k = tid; k < kn; k += 256) {
        const float4* kp = (const float4*)(Kb + ((size_t)(b * S_ + k) * HKV_ + kv) * HD_);
        const float4* q4 = (const float4*)qv;
        float s = 0.f;
#pragma unroll 8
        for (int i = 0; i < HD_ / 4; ++i) {
            float4 kk = kp[i];
            float4 qq = q4[i];
            s += kk.x * qq.x + kk.y * qq.y + kk.z * qq.z + kk.w * qq.w;
        }
        sc[k] = s;
        lmax = fmaxf(lmax, s);
    }
    red[tid] = lmax;
    __syncthreads();
    for (int s2 = 128; s2 > 0; s2 >>= 1) {
        if (tid < s2) red[tid] = fmaxf(red[tid], red[tid + s2]);
        __syncthreads();
    }
    float mx = red[0];
    __syncthreads();
    float lsum = 0.f;
    for (int k = tid; k < kn; k += 256) {
        float e = __expf(sc[k] - mx);
        sc[k] = e;
        lsum += e;
    }
    red[tid] = lsum;
    __syncthreads();
    for (int s2 = 128; s2 > 0; s2 >>= 1) {
        if (tid < s2) red[tid] += red[tid + s2];
        __syncthreads();
    }
    float inv = 1.0f / red[0];

    if (tid < HD_) {
        float acc = 0.f;
        const float* vp = Vb + ((size_t)(b * S_) * HKV_ + kv) * HD_ + tid;
#pragma unroll 4
        for (int k = 0; k < kn; ++k) acc += sc[k] * vp[(size_t)k * HKV_ * HD_];
        O[((size_t)(b * S_ + q) * HQ_ + h) * HD_ + tid] = acc * inv;
    }
}

// ---------------- router: per-token gate, top-2, combine + lb stats ----------------
// stats[0..E-1] = count of tokens choosing e ; stats[E..2E-1] = sum of probs
__global__ __launch_bounds__(256) void router_kernel(
    const float* __restrict__ h, const float* __restrict__ rscale,
    const float* __restrict__ wg, float* __restrict__ comb, float* __restrict__ stats)
{
    const int t = blockIdx.x;
    const int tid = threadIdx.x;
    const float* hp = h + (size_t)t * D_;
    float vals[8];
    float ss = 0.f;
#pragma unroll
    for (int i = 0; i < 8; ++i) {
        int d = tid + i * 256;
        float v = hp[d];
        vals[i] = v;
        ss += v * v;
    }
    __shared__ float red[256];
    red[tid] = ss;
    __syncthreads();
    for (int s = 128; s > 0; s >>= 1) {
        if (tid < s) red[tid] += red[tid + s];
        __syncthreads();
    }
    float rn = 1.0f / sqrtf(red[0] / (float)D_ + EPS_);
    __syncthreads();
    const float dsc = rn * 0.02209708691207961f;  // D^-0.5
    float part[E_] = {};
#pragma unroll
    for (int i = 0; i < 8; ++i) {
        int d = tid + i * 256;
        float g = vals[i] * dsc * rscale[d];
#pragma unroll
        for (int e = 0; e < E_; ++e) part[e] += g * wg[(size_t)d * E_ + e];
    }
    float lg[E_];
    for (int e = 0; e < E_; ++e) {
        red[tid] = part[e];
        __syncthreads();
        for (int s = 128; s > 0; s >>= 1) {
            if (tid < s) red[tid] += red[tid + s];
            __syncthreads();
        }
        lg[e] = red[0];
        __syncthreads();
    }
    if (tid == 0) {
        float m = lg[0];
        for (int e = 1; e < E_; ++e) m = fmaxf(m, lg[e]);
        float p[E_], sum = 0.f;
        for (int e = 0; e < E_; ++e) { p[e] = expf(lg[e] - m); sum += p[e]; }
        for (int e = 0; e < E_; ++e) p[e] /= sum;
        // top-2, first occurrence on ties (strict >)
        int i1 = 0;
        for (int e = 1; e < E_; ++e) if (p[e] > p[i1]) i1 = e;
        int i2 = (i1 == 0) ? 1 : 0;
        for (int e = 0; e < E_; ++e) if (e != i1 && p[e] > p[i2]) i2 = e;
        float wn = p[i1] + p[i2];
        for (int e = 0; e < E_; ++e) {
            float w = (e == i1) ? p[i1] / wn : (e == i2) ? p[i2] / wn : 0.f;
            comb[(size_t)t * E_ + e] = w;
        }
        atomicAdd(&stats[i1], 1.0f);
        atomicAdd(&stats[i2], 1.0f);
        for (int e = 0; e < E_; ++e) atomicAdd(&stats[E_ + e], p[e]);
    }
}

// ---------------- final: out = (rms(rout)*post_ff2 + sh + h) * ls ----------------
__global__ __launch_bounds__(256) void final_kernel(
    const float* __restrict__ rout, const float* __restrict__ post_ff2,
    const float* __restrict__ sh, const float* __restrict__ h,
    const float* __restrict__ lscalar, float* __restrict__ out)
{
    const int row = blockIdx.x;
    const int tid = threadIdx.x;
    const float* rp = rout + (size_t)row * D_;
    float vals[8];
    float ss = 0.f;
#pragma unroll
    for (int i = 0; i < 8; ++i) {
        int d = tid + i * 256;
        float v = rp[d];
        vals[i] = v;
        ss += v * v;
    }
    __shared__ float red[256];
    red[tid] = ss;
    __syncthreads();
    for (int s = 128; s > 0; s >>= 1) {
        if (tid < s) red[tid] += red[tid + s];
        __syncthreads();
    }
    float rn = 1.0f / sqrtf(red[0] / (float)D_ + EPS_);
    float ls = lscalar[0];
    const float* sp = sh + (size_t)row * D_;
    const float* hp = h + (size_t)row * D_;
    float* op = out + (size_t)row * D_;
#pragma unroll
    for (int i = 0; i < 8; ++i) {
        int d = tid + i * 256;
        op[d] = (vals[i] * rn * post_ff2[d] + sp[d] + hp[d]) * ls;
    }
}

// lb_loss = E * sum_e (cnt[e]/NT) * (psum[e]/NT)
__global__ void lb_kernel(const float* stats, float* out_loss)
{
    float acc = 0.f;
    for (int e = 0; e < E_; ++e) acc += stats[e] * stats[E_ + e];
    out_loss[0] = acc * (float)E_ / ((float)NT_ * (float)NT_);
}

// ---------------- launch ----------------
extern "C" void kernel_launch(void* const* d_in, const int* in_sizes, int n_in,
                              void* d_out, int out_size, void* d_ws, size_t ws_size,
                              hipStream_t stream)
{
    const int*   positions = (const int*)d_in[0];
    const float* x         = (const float*)d_in[1];
    const float* pre_attn  = (const float*)d_in[2];
    const float* wq        = (const float*)d_in[3];
    const float* wk        = (const float*)d_in[4];
    const float* wv        = (const float*)d_in[5];
    const float* wo        = (const float*)d_in[6];
    const float* q_ns      = (const float*)d_in[7];
    const float* k_ns      = (const float*)d_in[8];
    const float* v_ns      = (const float*)d_in[9];
    const float* post_attn = (const float*)d_in[10];
    const float* pre_ffw   = (const float*)d_in[11];
    const float* swi0      = (const float*)d_in[12];
    const float* swi1      = (const float*)d_in[13];
    const float* swo       = (const float*)d_in[14];
    const float* post_ff1  = (const float*)d_in[15];
    const float* pre_ff2   = (const float*)d_in[16];
    const float* rscale    = (const float*)d_in[17];
    const float* wgate     = (const float*)d_in[18];
    const float* ewi0      = (const float*)d_in[19];
    const float* ewi1      = (const float*)d_in[20];
    const float* ewo       = (const float*)d_in[21];
    const float* post_ff2  = (const float*)d_in[22];
    const float* lscalar   = (const float*)d_in[23];
    float* out = (float*)d_out;

    // workspace map (floats). Reuse: LNX=FFIN=RIN, Q=ROUT, K=T0, ATTN=SH.
    float* ws    = (float*)d_ws;
    float* LNX   = ws;                               // NT*D      (8M)
    float* Qb    = LNX  + (size_t)NT_ * D_;          // NT*HQ*HD  (8M)
    float* Kb    = Qb   + (size_t)NT_ * HQ_ * HD_;   // NT*HKV*HD (4M)
    float* Vb    = Kb   + (size_t)NT_ * HKV_ * HD_;  // NT*HKV*HD (4M)
    float* Ob    = Vb   + (size_t)NT_ * HKV_ * HD_;  // NT*HQ*HD  (8M)
    float* ATTNb = Ob   + (size_t)NT_ * HQ_ * HD_;   // NT*D      (8M)
    float* Hb    = ATTNb + (size_t)NT_ * D_;         // NT*D      (8M)
    float* SGb   = Hb   + (size_t)NT_ * D_;          // NT*FS     (32M)
    float* COMBb = SGb  + (size_t)NT_ * FS_;         // NT*E
    float* STATS = COMBb + (size_t)NT_ * E_;         // 2*E
    float* FFIN  = LNX;
    float* RIN   = LNX;
    float* ROUT  = Qb;
    float* T0    = Kb;
    float* SH    = ATTNb;

    // 1. lnx = rms(x)*pre_attn_scale
    rms_kernel<<<NT_, 256, 0, stream>>>(x, pre_attn, nullptr, LNX);

    // 2. q/k/v projections
    sgemm_kernel<0><<<dim3((HQ_ * HD_) / BN, NT_ / BM), 256, 0, stream>>>(
        LNX, wq, nullptr, Qb, NT_, HQ_ * HD_, D_, nullptr, 0, 0);
    sgemm_kernel<0><<<dim3((HKV_ * HD_) / BN, NT_ / BM), 256, 0, stream>>>(
        LNX, wk, nullptr, Kb, NT_, HKV_ * HD_, D_, nullptr, 0, 0);
    sgemm_kernel<0><<<dim3((HKV_ * HD_) / BN, NT_ / BM), 256, 0, stream>>>(
        LNX, wv, nullptr, Vb, NT_, HKV_ * HD_, D_, nullptr, 0, 0);

    // 3. head norms (+rope for q,k)
    headnorm_rope_kernel<<<NT_ * HQ_, 128, 0, stream>>>(Qb, q_ns, positions, HQ_, 1);
    headnorm_rope_kernel<<<NT_ * HKV_, 128, 0, stream>>>(Kb, k_ns, positions, HKV_, 1);
    headnorm_rope_kernel<<<NT_ * HKV_, 128, 0, stream>>>(Vb, v_ns, positions, HKV_, 0);

    // 4. attention
    attn_kernel<<<B_ * HQ_ * S_, 256, 0, stream>>>(Qb, Kb, Vb, Ob);

    // 5. attn = o @ wo ; then h = rms(attn)*post_attn + x
    sgemm_kernel<0><<<dim3(D_ / BN, NT_ / BM), 256, 0, stream>>>(
        Ob, wo, nullptr, ATTNb, NT_, D_, HQ_ * HD_, nullptr, 0, 0);
    rms_kernel<<<NT_, 256, 0, stream>>>(ATTNb, post_attn, x, Hb);

    // 6. shared FFN: ff_in = rms(h)*pre_ffw ; sg = gelu(ff@wi0)*(ff@wi1) ; sh = rms(sg@wo)*post_ff1
    rms_kernel<<<NT_, 256, 0, stream>>>(Hb, pre_ffw, nullptr, FFIN);
    sgemm_kernel<1><<<dim3(FS_ / BN, NT_ / BM), 256, 0, stream>>>(
        FFIN, swi0, swi1, SGb, NT_, FS_, D_, nullptr, 0, 0);
    sgemm_kernel<0><<<dim3(D_ / BN, NT_ / BM), 256, 0, stream>>>(
        SGb, swo, nullptr, SH, NT_, D_, FS_, nullptr, 0, 0);
    rms_kernel<<<NT_, 256, 0, stream>>>(SH, post_ff1, nullptr, SH);

    // 7. router (needs h) ; routed_in = rms(h)*pre_ff2
    rms_kernel<<<NT_, 256, 0, stream>>>(Hb, pre_ff2, nullptr, RIN);
    hipMemsetAsync(STATS, 0, 2 * E_ * sizeof(float), stream);
    router_kernel<<<NT_, 256, 0, stream>>>(Hb, rscale, wgate, COMBb, STATS);

    // 8. experts, dense, accumulated with combine weights in the epilogue
    for (int e = 0; e < E_; ++e) {
        const float* wi0e = ewi0 + (size_t)e * D_ * FE_;
        const float* wi1e = ewi1 + (size_t)e * D_ * FE_;
        const float* woe  = ewo  + (size_t)e * FE_ * D_;
        sgemm_kernel<1><<<dim3(FE_ / BN, NT_ / BM), 256, 0, stream>>>(
            RIN, wi0e, wi1e, T0, NT_, FE_, D_, nullptr, 0, 0);
        sgemm_kernel<2><<<dim3(D_ / BN, NT_ / BM), 256, 0, stream>>>(
            T0, woe, nullptr, ROUT, NT_, D_, FE_, COMBb + e, E_, e > 0 ? 1 : 0);
    }

    // 9. out = (rms(rout)*post_ff2 + sh + h) * layer_scalar ; lb_loss
    final_kernel<<<NT_, 256, 0, stream>>>(ROUT, post_ff2, SH, Hb, lscalar, out);
    lb_kernel<<<1, 1, 0, stream>>>(STATS, out + (size_t)NT_ * D_);
}